// Round 1
// baseline (796.024 us; speedup 1.0000x reference)
//
#include <hip/hip_runtime.h>
#include <cstdint>
#include <cstddef>

#define HD 128  // hidden channels

static inline int ceil_div(int a, int b) { return (a + b - 1) / b; }
static inline int imax(int a, int b) { return a > b ? a : b; }

// ---------------- CSR build ----------------

__global__ void k_hist(const int* __restrict__ ei, int nE,
                       int* __restrict__ degT, int* __restrict__ degS) {
  int e = blockIdx.x * blockDim.x + threadIdx.x;
  if (e >= nE) return;
  int s = ei[e];
  int t = ei[nE + e];
  atomicAdd(&degS[s], 1);
  atomicAdd(&degT[t], 1);
}

// one block per array (grid.x == 2); exclusive scan, off[n] = total
__global__ __launch_bounds__(1024) void k_exscan2(
    const int* __restrict__ degA, int* __restrict__ offA, int nA,
    const int* __restrict__ degB, int* __restrict__ offB, int nB) {
  const int* deg = (blockIdx.x == 0) ? degA : degB;
  int* off = (blockIdx.x == 0) ? offA : offB;
  int n = (blockIdx.x == 0) ? nA : nB;
  __shared__ int wsum[16];
  __shared__ int carry_s;
  int tid = threadIdx.x;
  int lane = tid & 63;
  int wid = tid >> 6;
  if (tid == 0) carry_s = 0;
  __syncthreads();
  for (int base = 0; base < n; base += 1024) {
    int i = base + tid;
    int v = (i < n) ? deg[i] : 0;
    int x = v;
#pragma unroll
    for (int d = 1; d < 64; d <<= 1) {
      int y = __shfl_up(x, d, 64);
      if (lane >= d) x += y;
    }
    if (lane == 63) wsum[wid] = x;
    __syncthreads();
    if (wid == 0) {
      int s = (lane < 16) ? wsum[lane] : 0;
#pragma unroll
      for (int d = 1; d < 16; d <<= 1) {
        int y = __shfl_up(s, d, 64);
        if (lane >= d) s += y;
      }
      if (lane < 16) wsum[lane] = s;
    }
    __syncthreads();
    int carry = carry_s;
    int wofs = (wid > 0) ? wsum[wid - 1] : 0;
    if (i < n) off[i] = carry + wofs + x - v;
    __syncthreads();
    if (tid == 0) carry_s = carry + wsum[15];
    __syncthreads();
  }
  if (tid == 0) off[n] = carry_s;
}

__global__ void k_fill(const int* __restrict__ ei, int nE,
                       const int* __restrict__ offT, int* __restrict__ curT, int* __restrict__ adjT,
                       const int* __restrict__ offS, int* __restrict__ curS, int* __restrict__ adjS) {
  int e = blockIdx.x * blockDim.x + threadIdx.x;
  if (e >= nE) return;
  int s = ei[e];
  int t = ei[nE + e];
  int pt = offT[t] + atomicAdd(&curT[t], 1);
  adjT[pt] = s;
  int ps = offS[s] + atomicAdd(&curS[s], 1);
  adjS[ps] = t;
}

// ---------------- scatter-mean (gather form over CSR) ----------------
// one wave per destination node; lane holds 2 channels (float2)
__global__ __launch_bounds__(256) void k_agg_mean(
    const float* __restrict__ xsrc, const int* __restrict__ smap,
    const int* __restrict__ off, const int* __restrict__ adj,
    float* __restrict__ agg, int ndst) {
  int gw = (int)((blockIdx.x * 256 + threadIdx.x) >> 6);
  int lane = threadIdx.x & 63;
  if (gw >= ndst) return;
  int beg = off[gw], end = off[gw + 1];
  float ax = 0.f, ay = 0.f;
  for (int k = beg; k < end; ++k) {
    int nsrc = adj[k];
    if (smap) nsrc = smap[nsrc];
    float2 v = ((const float2*)xsrc)[(size_t)nsrc * 64 + lane];
    ax += v.x;
    ay += v.y;
  }
  float inv = (end > beg) ? 1.0f / (float)(end - beg) : 0.0f;
  float2 r;
  r.x = ax * inv;
  r.y = ay * inv;
  ((float2*)agg)[(size_t)gw * 64 + lane] = r;
}

// ---------------- weight prep: wT[k][j] = concat(wl, wr) transposed ----------------
__global__ void k_build_wT(const float* __restrict__ wl, const float* __restrict__ wr,
                           float* __restrict__ wT) {
  int idx = blockIdx.x * blockDim.x + threadIdx.x;
  if (idx >= 256 * HD) return;
  int k = idx >> 7;
  int j = idx & (HD - 1);
  wT[idx] = (k < HD) ? wl[j * HD + k] : wr[j * HD + (k - HD)];
}

// ---------------- fused GEMM + bias + L2-norm + (leaky | residual) ----------------
// out[n][j] = post( (agg[n,:] @ wl^T + b + xdst[n,:] @ wr^T) )
// block = 256 threads, 32 rows per block; A_cat tile (32 x 256) staged in LDS (full K)
__global__ __launch_bounds__(256) void k_gemm_fused(
    const float* __restrict__ agg,   // [n,128]
    const float* __restrict__ xdst,  // base table [*,128]
    const int* __restrict__ xidx,    // may be null: row -> xdst row
    const float* __restrict__ wT,    // [256][128] (k-major)
    const float* __restrict__ bias,  // [128]
    const float* __restrict__ resid, // may be null, [n,128] (added AFTER norm)
    float* __restrict__ out, int n, int leaky) {
  __shared__ float As[32][256];
  int t = threadIdx.x;
  int base = blockIdx.x * 32;

  // stage A_cat: 32 rows x 256 cols = 2048 float4
  for (int f = t; f < 32 * 64; f += 256) {
    int r = f >> 6;
    int q = f & 63;
    int row = base + r;
    float4 v = make_float4(0.f, 0.f, 0.f, 0.f);
    if (row < n) {
      if (q < 32) {
        v = ((const float4*)(agg + (size_t)row * HD))[q];
      } else {
        int xr = xidx ? xidx[row] : row;
        v = ((const float4*)(xdst + (size_t)xr * HD))[q - 32];
      }
    }
    ((float4*)&As[0][0])[f] = v;
  }
  __syncthreads();

  int c = t & 63;  // columns c and c+64
  int h = t >> 6;  // wave id: rows h*8 .. h*8+7

  float acc[8][2];
  float b0 = bias[c];
  float b1 = bias[c + 64];
#pragma unroll
  for (int r = 0; r < 8; ++r) {
    acc[r][0] = b0;
    acc[r][1] = b1;
  }

  for (int k = 0; k < 256; k += 4) {
    float w0[4], w1[4];
#pragma unroll
    for (int kk = 0; kk < 4; ++kk) {
      w0[kk] = wT[(k + kk) * HD + c];
      w1[kk] = wT[(k + kk) * HD + c + 64];
    }
#pragma unroll
    for (int r = 0; r < 8; ++r) {
      float4 a = *((const float4*)&As[h * 8 + r][k]);
      acc[r][0] += a.x * w0[0] + a.y * w0[1] + a.z * w0[2] + a.w * w0[3];
      acc[r][1] += a.x * w1[0] + a.y * w1[1] + a.z * w1[2] + a.w * w1[3];
    }
  }

  // epilogue: per-row L2 norm over 128 cols (held by one wave, 2 cols/lane)
#pragma unroll
  for (int r = 0; r < 8; ++r) {
    int row = base + h * 8 + r;
    float ss = acc[r][0] * acc[r][0] + acc[r][1] * acc[r][1];
#pragma unroll
    for (int ofs = 32; ofs > 0; ofs >>= 1) ss += __shfl_xor(ss, ofs, 64);
    float nrm = sqrtf(ss);
    float inv = 1.0f / fmaxf(nrm, 1e-12f);
    float v0 = acc[r][0] * inv;
    float v1 = acc[r][1] * inv;
    if (leaky) {
      v0 = (v0 > 0.f) ? v0 : 0.01f * v0;
      v1 = (v1 > 0.f) ? v1 : 0.01f * v1;
    }
    if (row < n) {
      if (resid) {
        v0 += resid[(size_t)row * HD + c];
        v1 += resid[(size_t)row * HD + c + 64];
      }
      out[(size_t)row * HD + c] = v0;
      out[(size_t)row * HD + c + 64] = v1;
    }
  }
}

// ---------------- classifier: dot(h3_s[a], h3_t[b]) per label edge ----------------
__global__ __launch_bounds__(256) void k_classifier(
    const int* __restrict__ eli, int nL,
    const float* __restrict__ h3s, const float* __restrict__ h3t,
    float* __restrict__ out) {
  int w = (int)((blockIdx.x * 256 + threadIdx.x) >> 6);
  int lane = threadIdx.x & 63;
  if (w >= nL) return;
  int s = eli[w];
  int t = eli[nL + w];
  float2 a = ((const float2*)h3s)[(size_t)s * 64 + lane];
  float2 b = ((const float2*)h3t)[(size_t)t * 64 + lane];
  float p = a.x * b.x + a.y * b.y;
#pragma unroll
  for (int ofs = 32; ofs > 0; ofs >>= 1) p += __shfl_xor(p, ofs, 64);
  if (lane == 0) out[w] = p;
}

extern "C" void kernel_launch(void* const* d_in, const int* in_sizes, int n_in,
                              void* d_out, int out_size, void* d_ws, size_t ws_size,
                              hipStream_t stream) {
  (void)n_in;
  (void)out_size;
  const int* snid = (const int*)d_in[0];
  const int* tnid = (const int*)d_in[1];
  const int* ei = (const int*)d_in[2];
  const int* eli = (const int*)d_in[3];
  const float* semb = (const float*)d_in[4];
  const float* temb = (const float*)d_in[5];
  const float* w1l_bt = (const float*)d_in[6];
  const float* w1r_bt = (const float*)d_in[7];
  const float* w1l_tb = (const float*)d_in[8];
  const float* w1r_tb = (const float*)d_in[9];
  const float* w2l_bt = (const float*)d_in[10];
  const float* w2r_bt = (const float*)d_in[11];
  const float* w2l_tb = (const float*)d_in[12];
  const float* w2r_tb = (const float*)d_in[13];
  const float* b1_bt = (const float*)d_in[14];
  const float* b1_tb = (const float*)d_in[15];
  const float* b2_bt = (const float*)d_in[16];
  const float* b2_tb = (const float*)d_in[17];

  const int NS_ = in_sizes[0];
  const int NT_ = in_sizes[1];
  const int nE = in_sizes[2] / 2;
  const int nL = in_sizes[3] / 2;
  float* out = (float*)d_out;

  char* ws = (char*)d_ws;
  size_t o = 0;
  auto alloc = [&](size_t bytes) -> void* {
    void* p = ws + o;
    o = (o + bytes + 255) & ~(size_t)255;
    return p;
  };
  int* off_t_ = (int*)alloc(((size_t)NT_ + 1) * 4);
  int* off_s_ = (int*)alloc(((size_t)NS_ + 1) * 4);
  int* cur_t_ = (int*)alloc((size_t)NT_ * 4);
  int* cur_s_ = (int*)alloc((size_t)NS_ * 4);
  int* adj_t_ = (int*)alloc((size_t)nE * 4);
  int* adj_s_ = (int*)alloc((size_t)nE * 4);
  float* wT1 = (float*)alloc(256 * HD * 4);
  float* wT2 = (float*)alloc(256 * HD * 4);
  float* wT3 = (float*)alloc(256 * HD * 4);
  float* wT4 = (float*)alloc(256 * HD * 4);
  int nmax = imax(NS_, NT_);
  float* agg = (float*)alloc((size_t)nmax * HD * 4);
  float* h1s = (float*)alloc((size_t)NS_ * HD * 4);
  float* h1t = (float*)alloc((size_t)NT_ * HD * 4);
  float* h3s = (float*)alloc((size_t)NS_ * HD * 4);
  float* h3t = (float*)alloc((size_t)NT_ * HD * 4);
  if (o > ws_size) return;  // workspace insufficient — fail loudly (poison output)

  // ---- CSR build (both directions) ----
  hipMemsetAsync(cur_t_, 0, (size_t)NT_ * 4, stream);
  hipMemsetAsync(cur_s_, 0, (size_t)NS_ * 4, stream);
  k_hist<<<ceil_div(nE, 256), 256, 0, stream>>>(ei, nE, cur_t_, cur_s_);
  k_exscan2<<<2, 1024, 0, stream>>>(cur_t_, off_t_, NT_, cur_s_, off_s_, NS_);
  hipMemsetAsync(cur_t_, 0, (size_t)NT_ * 4, stream);
  hipMemsetAsync(cur_s_, 0, (size_t)NS_ * 4, stream);
  k_fill<<<ceil_div(nE, 256), 256, 0, stream>>>(ei, nE, off_t_, cur_t_, adj_t_,
                                                off_s_, cur_s_, adj_s_);

  // ---- weight prep ----
  int wgrid = ceil_div(256 * HD, 256);
  k_build_wT<<<wgrid, 256, 0, stream>>>(w1l_bt, w1r_bt, wT1);
  k_build_wT<<<wgrid, 256, 0, stream>>>(w1l_tb, w1r_tb, wT2);
  k_build_wT<<<wgrid, 256, 0, stream>>>(w2l_bt, w2r_bt, wT3);
  k_build_wT<<<wgrid, 256, 0, stream>>>(w2l_tb, w2r_tb, wT4);

  // ---- layer 1 ----
  // conv1_t: msgs = semb[snid[si]] -> targets; xdst = temb[tnid[row]]
  k_agg_mean<<<ceil_div(NT_, 4), 256, 0, stream>>>(semb, snid, off_t_, adj_t_, agg, NT_);
  k_gemm_fused<<<ceil_div(NT_, 32), 256, 0, stream>>>(agg, temb, tnid, wT1, b1_bt, nullptr,
                                                      h1t, NT_, 1);
  // conv1_s
  k_agg_mean<<<ceil_div(NS_, 4), 256, 0, stream>>>(temb, tnid, off_s_, adj_s_, agg, NS_);
  k_gemm_fused<<<ceil_div(NS_, 32), 256, 0, stream>>>(agg, semb, snid, wT2, b1_tb, nullptr,
                                                      h1s, NS_, 1);

  // ---- layer 2 (residual fused: h3 = h1 + norm(gemm)) ----
  k_agg_mean<<<ceil_div(NT_, 4), 256, 0, stream>>>(h1s, nullptr, off_t_, adj_t_, agg, NT_);
  k_gemm_fused<<<ceil_div(NT_, 32), 256, 0, stream>>>(agg, h1t, nullptr, wT3, b2_bt, h1t,
                                                      h3t, NT_, 0);
  k_agg_mean<<<ceil_div(NS_, 4), 256, 0, stream>>>(h1t, nullptr, off_s_, adj_s_, agg, NS_);
  k_gemm_fused<<<ceil_div(NS_, 32), 256, 0, stream>>>(agg, h1s, nullptr, wT4, b2_tb, h1s,
                                                      h3s, NS_, 0);

  // ---- classifier ----
  k_classifier<<<ceil_div(nL, 4), 256, 0, stream>>>(eli, nL, h3s, h3t, out);
}